// Round 16
// baseline (94.327 us; speedup 1.0000x reference)
//
#include <hip/hip_runtime.h>
#include <hip/hip_bf16.h>

typedef float  f32x2  __attribute__((ext_vector_type(2)));
typedef float  f32x4  __attribute__((ext_vector_type(4)));
typedef float  f32x16 __attribute__((ext_vector_type(16)));
typedef short  short8 __attribute__((ext_vector_type(8)));
typedef int    i32x2  __attribute__((ext_vector_type(2)));
typedef unsigned int uint4v __attribute__((ext_vector_type(4)));

#define N_  2
#define L_  4096
#define S_  4096
#define H_  8
#define D_  64
#define HD_ 512        // H_*D_
#define KVB 64
#define QB  128        // q-rows per block (2 q-waves x 64)
#define NT  64         // S/KVB tiles; each wave does its 32-s half of every tile

// fp32 -> bf16 (round-nearest-even), manual
__device__ __forceinline__ unsigned short f2bf(float f) {
  unsigned int u = __builtin_bit_cast(unsigned int, f);
  u += 0x7fffu + ((u >> 16) & 1u);
  return (unsigned short)(u >> 16);
}
__device__ __forceinline__ unsigned short bf16c(float f) {
  return __builtin_bit_cast(unsigned short, __float2bfloat16(f));
}
// v_cvt_pk_bf16_f32 (no builtin on gfx950)
__device__ __forceinline__ unsigned int pk2(float lo, float hi) {
  unsigned int r;
  asm("v_cvt_pk_bf16_f32 %0, %1, %2" : "=v"(r) : "v"(lo), "v"(hi));
  return r;
}
// packed 2xf32 add (v_pk_add_f32, gfx90a+): halves the tsum instruction count
__device__ __forceinline__ f32x2 pkadd(f32x2 a, f32x2 b) {
  f32x2 r;
  asm("v_pk_add_f32 %0, %1, %2" : "=v"(r) : "v"(a), "v"(b));
  return r;
}
__device__ __forceinline__ f32x16 zero16() {
  f32x16 v;
  #pragma unroll
  for (int i = 0; i < 16; ++i) v[i] = 0.f;
  return v;
}
// tree-sum of 16 floats via 7 v_pk_add_f32 + 1 v_add (was 15 v_add)
__device__ __forceinline__ float tsum16pk(const f32x16& v) {
  f32x2 p0 = {v[0],  v[1]},  p1 = {v[2],  v[3]};
  f32x2 p2 = {v[4],  v[5]},  p3 = {v[6],  v[7]};
  f32x2 p4 = {v[8],  v[9]},  p5 = {v[10], v[11]};
  f32x2 p6 = {v[12], v[13]}, p7 = {v[14], v[15]};
  f32x2 a = pkadd(p0, p1), b = pkadd(p2, p3);
  f32x2 c = pkadd(p4, p5), d = pkadd(p6, p7);
  f32x2 e = pkadd(a, b),   f = pkadd(c, d);
  f32x2 g = pkadd(e, f);
  return g[0] + g[1];
}

// ---------------------------------------------------------------------------
// Pre-pass: K,V fp32 -> bf16 fragment-contiguous tile images (direct-VMEM).
// K image (per nh,t): elem = (d>>3)*512 + s*8 + (d&7)
// V image (per nh,t): elem = (s>>3)*512 + d*8 + (s&7)
// ---------------------------------------------------------------------------
__global__ __launch_bounds__(256, 8)
void prepack(const float* __restrict__ Kg, const float* __restrict__ Vg,
             unsigned short* __restrict__ Kw, unsigned short* __restrict__ Vw) {
  const int b = blockIdx.x;             // 0..2047
  const int tid = threadIdx.x;
  const int isV = (b >= 1024);
  const int tb = isV ? b - 1024 : b;    // (nh, t) tile id
  const int nh = tb >> 6, t = tb & 63;
  const int n = nh >> 3, h = nh & 7;

  if (!isV) {
    const int sl = tid >> 2, d0 = (tid & 3) << 4;
    const float* src = Kg + ((size_t)(n * S_ + t * 64 + sl) * H_ + h) * D_ + d0;
    f32x4 x0 = *(const f32x4*)(src);
    f32x4 x1 = *(const f32x4*)(src + 4);
    f32x4 x2 = *(const f32x4*)(src + 8);
    f32x4 x3 = *(const f32x4*)(src + 12);
    short8 t0, t1;
    t0[0] = (short)f2bf(x0[0]); t0[1] = (short)f2bf(x0[1]);
    t0[2] = (short)f2bf(x0[2]); t0[3] = (short)f2bf(x0[3]);
    t0[4] = (short)f2bf(x1[0]); t0[5] = (short)f2bf(x1[1]);
    t0[6] = (short)f2bf(x1[2]); t0[7] = (short)f2bf(x1[3]);
    t1[0] = (short)f2bf(x2[0]); t1[1] = (short)f2bf(x2[1]);
    t1[2] = (short)f2bf(x2[2]); t1[3] = (short)f2bf(x2[3]);
    t1[4] = (short)f2bf(x3[0]); t1[5] = (short)f2bf(x3[1]);
    t1[6] = (short)f2bf(x3[2]); t1[7] = (short)f2bf(x3[3]);
    unsigned short* dst = Kw + (size_t)tb * 4096;
    const int b0 = d0 >> 3;
    *(short8*)&dst[(b0)     * 512 + sl * 8] = t0;
    *(short8*)&dst[(b0 + 1) * 512 + sl * 8] = t1;
  } else {
    const int d = tid & 63, sb2 = tid >> 6;
    #pragma unroll
    for (int c = 0; c < 2; ++c) {
      const int sblk = sb2 * 2 + c;
      const float* src = Vg + ((size_t)(n * S_ + t * 64 + sblk * 8) * H_ + h) * D_ + d;
      short8 o;
      #pragma unroll
      for (int j = 0; j < 8; ++j) o[j] = (short)f2bf(src[(size_t)j * HD_]);
      *(short8*)&Vw[(size_t)tb * 4096 + sblk * 512 + d * 8] = o;
    }
  }
}

// build pa0/pa1 (A-frags for s-chunks 0-15 / 16-31) from a 16-score vector
__device__ __forceinline__ void mk_pa(const f32x16& s, short8& pa0, short8& pa1) {
  {
    const unsigned int c0 = pk2(s[0], s[1]);
    const unsigned int c1 = pk2(s[2], s[3]);
    const unsigned int c2 = pk2(s[4], s[5]);
    const unsigned int c3 = pk2(s[6], s[7]);
    i32x2 r0 = __builtin_amdgcn_permlane32_swap((int)c0, (int)c2, false, false);
    i32x2 r1 = __builtin_amdgcn_permlane32_swap((int)c1, (int)c3, false, false);
    uint4v w = { (unsigned)r0[0], (unsigned)r1[0], (unsigned)r0[1], (unsigned)r1[1] };
    pa0 = __builtin_bit_cast(short8, w);
  }
  {
    const unsigned int c0 = pk2(s[8],  s[9]);
    const unsigned int c1 = pk2(s[10], s[11]);
    const unsigned int c2 = pk2(s[12], s[13]);
    const unsigned int c3 = pk2(s[14], s[15]);
    i32x2 r0 = __builtin_amdgcn_permlane32_swap((int)c0, (int)c2, false, false);
    i32x2 r1 = __builtin_amdgcn_permlane32_swap((int)c1, (int)c3, false, false);
    uint4v w = { (unsigned)r0[0], (unsigned)r1[0], (unsigned)r0[1], (unsigned)r1[1] };
    pa1 = __builtin_bit_cast(short8, w);
  }
}

// ---------------------------------------------------------------------------
// Tile body: 64 q-rows/wave (2 q-blocks A,B), 32-s slice of tile; next tile
// ttn prefetched. 8 loads feed 16 MFMA. Serial-chain micro-cuts (r15):
// first QK MFMA uses the persistent pinned-zero C operand (no per-tile
// 32x v_mov re-zeroing), tsum via v_pk_add_f32 tree.
// ---------------------------------------------------------------------------
template<int DOK, int DOV>
__device__ __forceinline__ void tile_body(
    int ttn, const char* kbase, const char* vbase, const f32x16& kz,
    const short8 qfA[4], const short8 qfB[4], short8 kf[4], short8 vf[4],
    f32x16& accA0, f32x16& accA1, f32x16& accB0, f32x16& accB1,
    float& lsumA, float& lsumB)
{
  __builtin_amdgcn_s_setprio(1);
  f32x16 sA = __builtin_amdgcn_mfma_f32_32x32x16_bf16(kf[0], qfA[0], kz, 0, 0, 0);
  f32x16 sB = __builtin_amdgcn_mfma_f32_32x32x16_bf16(kf[0], qfB[0], kz, 0, 0, 0);
  #pragma unroll
  for (int kc = 1; kc < 4; ++kc) {
    sA = __builtin_amdgcn_mfma_f32_32x32x16_bf16(kf[kc], qfA[kc], sA, 0, 0, 0);
    sB = __builtin_amdgcn_mfma_f32_32x32x16_bf16(kf[kc], qfB[kc], sB, 0, 0, 0);
  }
  __builtin_amdgcn_s_setprio(0);

  if (DOK) {  // prefetch kf[ttn] (compiler renames regs -> auto double-buffer)
    const char* kp = kbase + (size_t)ttn * 8192;
    #pragma unroll
    for (int kc = 0; kc < 4; ++kc)
      kf[kc] = *(const short8*)(kp + kc * 2048);
  }

  #pragma unroll
  for (int r = 0; r < 16; ++r) sA[r] = __builtin_amdgcn_exp2f(sA[r]);
  lsumA += tsum16pk(sA);
  #pragma unroll
  for (int r = 0; r < 16; ++r) sB[r] = __builtin_amdgcn_exp2f(sB[r]);
  lsumB += tsum16pk(sB);

  short8 paA0, paA1, paB0, paB1;
  mk_pa(sA, paA0, paA1);
  __builtin_amdgcn_s_setprio(1);
  accA0 = __builtin_amdgcn_mfma_f32_32x32x16_bf16(paA0, vf[0], accA0, 0, 0, 0);
  accA1 = __builtin_amdgcn_mfma_f32_32x32x16_bf16(paA0, vf[1], accA1, 0, 0, 0);
  accA0 = __builtin_amdgcn_mfma_f32_32x32x16_bf16(paA1, vf[2], accA0, 0, 0, 0);
  accA1 = __builtin_amdgcn_mfma_f32_32x32x16_bf16(paA1, vf[3], accA1, 0, 0, 0);
  __builtin_amdgcn_s_setprio(0);
  mk_pa(sB, paB0, paB1);
  __builtin_amdgcn_s_setprio(1);
  accB0 = __builtin_amdgcn_mfma_f32_32x32x16_bf16(paB0, vf[0], accB0, 0, 0, 0);
  accB1 = __builtin_amdgcn_mfma_f32_32x32x16_bf16(paB0, vf[1], accB1, 0, 0, 0);
  accB0 = __builtin_amdgcn_mfma_f32_32x32x16_bf16(paB1, vf[2], accB0, 0, 0, 0);
  accB1 = __builtin_amdgcn_mfma_f32_32x32x16_bf16(paB1, vf[3], accB1, 0, 0, 0);
  __builtin_amdgcn_s_setprio(0);

  if (DOV) {  // prefetch vf[ttn]
    const char* vp = vbase + (size_t)ttn * 8192;
    #pragma unroll
    for (int q4 = 0; q4 < 4; ++q4)
      vf[q4] = *(const short8*)(vp + (q4 >> 1) * 2048 + (q4 & 1) * 512);
  }
}

// ---------------------------------------------------------------------------
// 256-thread blocks: 2 q-waves(64q each) x 2 s-halves. Barrier-free loop,
// block-parity tile rotation (r14, +2.5%). Persistent pinned-zero C operand.
// __launch_bounds__(256,2): empirical hipcc rule = VGPR cap 256/arg = 128.
// ---------------------------------------------------------------------------
__global__ __launch_bounds__(256, 2)
void attn_fa13(const float* __restrict__ Qg,
               const unsigned short* __restrict__ Kw,
               const unsigned short* __restrict__ Vw,
               float* __restrict__ Og) {
  __shared__ __align__(16) float Comb[2][4096];   // 32 KiB (epilogue only)
  __shared__ float CombL[2][64];                  // 512 B

  const int tid = threadIdx.x;
  const int wv  = tid >> 6;       // 0..3
  const int qw  = wv & 1;         // q-wave (64 q each)
  const int sh  = wv >> 1;        // s-half within each tile
  const int ln  = tid & 63;
  const int hi  = ln >> 5;
  const int c32 = ln & 31;

  const int bid = blockIdx.x;
  const int swz = (bid & 7) * 64 + (bid >> 3);   // XCD-contiguous
  const int qt  = swz & 31;
  const int nh  = swz >> 5;                      // 2 nh per XCD -> K/V L2-resident
  const int p   = (bid >> 3) & 1;                // co-resident-block parity
  const int h = nh & 7, n = nh >> 3;
  const int qbase = qt * QB + qw * 64;

  // ---- Q fragments for both q-blocks, scaled by 1/sqrt(D)*log2(e) ----
  const float qs = 0.125f * 1.44269504088896340736f;
  short8 qfA[4], qfB[4];
  #pragma unroll
  for (int b = 0; b < 2; ++b) {
    const int qrow = qbase + b * 32 + c32;
    const float* qp = Qg + (size_t)(n * L_ + qrow) * HD_ + h * D_ + (hi << 3);
    #pragma unroll
    for (int kc = 0; kc < 4; ++kc) {
      const float* pp = qp + (kc << 4);
      f32x4 a = *(const f32x4*)(pp);
      f32x4 bx = *(const f32x4*)(pp + 4);
      short8 f;
      f[0] = (short)bf16c(a[0] * qs);  f[1] = (short)bf16c(a[1] * qs);
      f[2] = (short)bf16c(a[2] * qs);  f[3] = (short)bf16c(a[3] * qs);
      f[4] = (short)bf16c(bx[0] * qs); f[5] = (short)bf16c(bx[1] * qs);
      f[6] = (short)bf16c(bx[2] * qs); f[7] = (short)bf16c(bx[3] * qs);
      if (b == 0) qfA[kc] = f; else qfB[kc] = f;
    }
  }

  // persistent zero C-operand: zeroed once, pinned so the compiler keeps it
  // as a live 16-VGPR tuple instead of re-materializing 32 v_movs per tile.
  f32x16 kz = zero16();
  asm volatile("" : "+v"(kz));

  f32x16 accA0 = kz, accA1 = kz, accB0 = kz, accB1 = kz;
  float lsumA = 0.f, lsumB = 0.f;

  // per-lane global bases; s-slice = [sh*32, sh*32+32) of every tile
  const char* kbase = (const char*)(Kw + (size_t)nh * 64 * 4096)
                      + (hi << 10) + (sh << 9) + (c32 << 4);
  const char* vbase = (const char*)(Vw + (size_t)nh * 64 * 4096)
                      + (sh << 12) + (hi << 10) + (c32 << 4);

  short8 kf[4], vf[4];
  int tt = p << 5;                  // start tile: 0 or 32 per block parity
  {
    const char* kp = kbase + (size_t)tt * 8192;
    #pragma unroll
    for (int kc = 0; kc < 4; ++kc)
      kf[kc] = *(const short8*)(kp + kc * 2048);
    const char* vp = vbase + (size_t)tt * 8192;
    #pragma unroll
    for (int q4 = 0; q4 < 4; ++q4)
      vf[q4] = *(const short8*)(vp + (q4 >> 1) * 2048 + (q4 & 1) * 512);
  }

  for (int t = 0; t < NT - 1; ++t) {
    const int ttn = (tt + 1) & 63;
    tile_body<1, 1>(ttn, kbase, vbase, kz, qfA, qfB, kf, vf,
                    accA0, accA1, accB0, accB1, lsumA, lsumB);
    tt = ttn;
  }
  tile_body<0, 0>(0, kbase, vbase, kz, qfA, qfB, kf, vf,
                  accA0, accA1, accB0, accB1, lsumA, lsumB);

  // ---- epilogue: combine the two s-halves through LDS, normalize, store ----
  const float fullA = lsumA + __shfl_xor(lsumA, 32);   // row sum, q = c32
  const float fullB = lsumB + __shfl_xor(lsumB, 32);   // row sum, q = 32+c32
  float* C = &Comb[qw][0];                             // 64q x 64d

  if (sh == 1) {
    #pragma unroll
    for (int r = 0; r < 16; ++r) {
      const int q = (r & 3) + 8 * (r >> 2) + 4 * hi;
      C[q * 64 + c32]             = accA0[r];
      C[q * 64 + 32 + c32]        = accA1[r];
      C[(32 + q) * 64 + c32]      = accB0[r];
      C[(32 + q) * 64 + 32 + c32] = accB1[r];
    }
    if (hi == 0) { CombL[qw][c32] = fullA; CombL[qw][32 + c32] = fullB; }
  }
  __syncthreads();
  if (sh == 0) {
    const float ltotA = fullA + CombL[qw][c32];
    const float ltotB = fullB + CombL[qw][32 + c32];
    #pragma unroll
    for (int r = 0; r < 16; ++r) {
      const int q = (r & 3) + 8 * (r >> 2) + 4 * hi;
      const float lA = __shfl(ltotA, q);
      const float lB = __shfl(ltotB, q);
      const int rowA = qbase + q;
      const int rowB = qbase + 32 + q;
      float* opA = Og + (size_t)(n * L_ + rowA) * HD_ + h * D_ + c32;
      float* opB = Og + (size_t)(n * L_ + rowB) * HD_ + h * D_ + c32;
      opA[0]  = (accA0[r] + C[q * 64 + c32])             / lA;
      opA[32] = (accA1[r] + C[q * 64 + 32 + c32])        / lA;
      opB[0]  = (accB0[r] + C[(32 + q) * 64 + c32])      / lB;
      opB[32] = (accB1[r] + C[(32 + q) * 64 + 32 + c32]) / lB;
    }
  }
}

extern "C" void kernel_launch(void* const* d_in, const int* in_sizes, int n_in,
                              void* d_out, int out_size, void* d_ws, size_t ws_size,
                              hipStream_t stream) {
  (void)in_sizes; (void)n_in; (void)out_size; (void)ws_size;
  const float* Q = (const float*)d_in[0];
  const float* K = (const float*)d_in[1];
  const float* V = (const float*)d_in[2];
  float* O = (float*)d_out;

  unsigned short* Kw = (unsigned short*)d_ws;            // 8 MiB
  unsigned short* Vw = Kw + 4194304;                     // 8 MiB (ws >= 16 MiB verified)
  hipLaunchKernelGGL(prepack, dim3(2048), dim3(256), 0, stream, K, V, Kw, Vw);
  hipLaunchKernelGGL(attn_fa13, dim3(512), dim3(256), 0, stream, Q, Kw, Vw, O);
}